// Round 1
// baseline (2246.905 us; speedup 1.0000x reference)
//
#include <hip/hip_runtime.h>

#define HD 128
#define LD 2048
#define BD 64
#define VD 32000
#define NSTEP 2047   // L-1 scan steps, t = 0..2046

// f32 constants exactly matching the reference's f32-cast scalars
#define C_ALPHA  0.05f    // (1.0 - 0.95) rounded to f32
#define C_THMIN  0.4f
#define C_THSPAN 1.1f     // (1.5 - 0.4) rounded to f32
#define C_NEPS   1e-12f
#define C_LNEPS  1e-5f

// ---------------------------------------------------------------------------
// K1: fused embed-gather + MLP (h@w1,relu,@w2,+h,+b2) + LayerNorm + keys=hn@kp
// 128 tokens per block, 256 threads. Dynamic LDS = 137216 B.
// ---------------------------------------------------------------------------
#define HSP 132   // h / hn tile pitch   [128][132]
#define W1P 68    // w1 tile pitch       [128][68]
#define W2P 132   // w2 / kp tile pitch  [64][132]
#define ATP 68    // a tile pitch        [128][68]

extern "C" __global__ __launch_bounds__(256, 1)
void k_tokens(const int* __restrict__ seq, const float* __restrict__ embed,
              const float* __restrict__ w1, const float* __restrict__ b1,
              const float* __restrict__ w2, const float* __restrict__ b2,
              const float* __restrict__ lng, const float* __restrict__ lnb,
              const float* __restrict__ kp, float* __restrict__ keys)
{
  extern __shared__ float sm[];
  float* hs = sm;                 // [128][HSP]  h, later hn
  float* wt = sm + 128*HSP;       // [128][W1P] (w1 tile) or [64][W2P] (w2/kp)
  float* at = wt + 128*W1P;       // [128][ATP]  relu tile
  const int tid = threadIdx.x;
  const long long tokBase = (long long)blockIdx.x * 128;

  // ---- gather h = embed[seq]
  for (int u = tid; u < 128*32; u += 256) {
    const int tok = u >> 5, seg = u & 31;
    const int s = seq[tokBase + tok];
    *(float4*)(hs + tok*HSP + seg*4) =
        *(const float4*)(embed + (long long)s*HD + seg*4);
  }
  __syncthreads();

  const int tg = tid >> 4;   // token group: tok = tg + 16*r, r=0..7
  const int ig = tid & 15;   // column group

  float xacc[8][8] = {};     // x (MLP out) accumulator: 8 tok x 8 i

  for (int jt = 0; jt < 4; ++jt) {
    // stage w1 tile [128 i][64 j]
    for (int u = tid; u < 128*16; u += 256) {
      const int i = u >> 4, q = u & 15;
      *(float4*)(wt + i*W1P + q*4) =
          *(const float4*)(w1 + (long long)i*256 + jt*64 + q*4);
    }
    __syncthreads();
    // a-tile = relu(h @ w1tile + b1): thread = 8 tok x 4 j
    {
      float aa[8][4];
      float b1v[4];
      #pragma unroll
      for (int c = 0; c < 4; ++c) b1v[c] = b1[jt*64 + ig*4 + c];
      #pragma unroll
      for (int r = 0; r < 8; ++r)
        #pragma unroll
        for (int c = 0; c < 4; ++c) aa[r][c] = b1v[c];
      #pragma unroll 4
      for (int i4 = 0; i4 < 32; ++i4) {
        float wc[4][4];
        #pragma unroll
        for (int d = 0; d < 4; ++d) {
          float4 u = *(const float4*)(wt + (i4*4 + d)*W1P + ig*4);
          wc[d][0] = u.x; wc[d][1] = u.y; wc[d][2] = u.z; wc[d][3] = u.w;
        }
        #pragma unroll
        for (int r = 0; r < 8; ++r) {
          float4 hv = *(const float4*)(hs + (tg + 16*r)*HSP + i4*4);
          #pragma unroll
          for (int c = 0; c < 4; ++c) {
            aa[r][c] = fmaf(hv.x, wc[0][c], aa[r][c]);
            aa[r][c] = fmaf(hv.y, wc[1][c], aa[r][c]);
            aa[r][c] = fmaf(hv.z, wc[2][c], aa[r][c]);
            aa[r][c] = fmaf(hv.w, wc[3][c], aa[r][c]);
          }
        }
      }
      #pragma unroll
      for (int r = 0; r < 8; ++r) {
        float4 o;
        o.x = fmaxf(aa[r][0], 0.0f); o.y = fmaxf(aa[r][1], 0.0f);
        o.z = fmaxf(aa[r][2], 0.0f); o.w = fmaxf(aa[r][3], 0.0f);
        *(float4*)(at + (tg + 16*r)*ATP + ig*4) = o;
      }
    }
    __syncthreads();
    // stage w2 tile [64 k][128 i] (overwrites w1 tile)
    for (int u = tid; u < 64*32; u += 256) {
      const int k = u >> 5, q = u & 31;
      *(float4*)(wt + k*W2P + q*4) =
          *(const float4*)(w2 + (long long)(jt*64 + k)*128 + q*4);
    }
    __syncthreads();
    // x += a-tile @ w2tile: thread = 8 tok x 8 i
    #pragma unroll 2
    for (int k4 = 0; k4 < 16; ++k4) {
      float wr[4][8];
      #pragma unroll
      for (int d = 0; d < 4; ++d) {
        float4 u0 = *(const float4*)(wt + (k4*4 + d)*W2P + ig*8);
        float4 u1 = *(const float4*)(wt + (k4*4 + d)*W2P + ig*8 + 4);
        wr[d][0]=u0.x; wr[d][1]=u0.y; wr[d][2]=u0.z; wr[d][3]=u0.w;
        wr[d][4]=u1.x; wr[d][5]=u1.y; wr[d][6]=u1.z; wr[d][7]=u1.w;
      }
      #pragma unroll
      for (int r = 0; r < 8; ++r) {
        float4 av = *(const float4*)(at + (tg + 16*r)*ATP + k4*4);
        #pragma unroll
        for (int cc = 0; cc < 8; ++cc) {
          xacc[r][cc] = fmaf(av.x, wr[0][cc], xacc[r][cc]);
          xacc[r][cc] = fmaf(av.y, wr[1][cc], xacc[r][cc]);
          xacc[r][cc] = fmaf(av.z, wr[2][cc], xacc[r][cc]);
          xacc[r][cc] = fmaf(av.w, wr[3][cc], xacc[r][cc]);
        }
      }
    }
    __syncthreads();
  }

  // ---- x = h + (x + b2); LayerNorm over i (16 lanes share a token); hn -> hs
  {
    float b2v[8], gv[8], bv[8];
    #pragma unroll
    for (int cc = 0; cc < 8; ++cc) {
      b2v[cc] = b2[ig*8 + cc]; gv[cc] = lng[ig*8 + cc]; bv[cc] = lnb[ig*8 + cc];
    }
    #pragma unroll
    for (int r = 0; r < 8; ++r) {
      const int row = (tg + 16*r)*HSP + ig*8;
      float4 h0 = *(const float4*)(hs + row);
      float4 h1 = *(const float4*)(hs + row + 4);
      float xr[8];
      xr[0] = h0.x + (xacc[r][0] + b2v[0]);
      xr[1] = h0.y + (xacc[r][1] + b2v[1]);
      xr[2] = h0.z + (xacc[r][2] + b2v[2]);
      xr[3] = h0.w + (xacc[r][3] + b2v[3]);
      xr[4] = h1.x + (xacc[r][4] + b2v[4]);
      xr[5] = h1.y + (xacc[r][5] + b2v[5]);
      xr[6] = h1.z + (xacc[r][6] + b2v[6]);
      xr[7] = h1.w + (xacc[r][7] + b2v[7]);
      float s = xr[0]+xr[1]+xr[2]+xr[3]+xr[4]+xr[5]+xr[6]+xr[7];
      s += __shfl_xor(s, 1, 16); s += __shfl_xor(s, 2, 16);
      s += __shfl_xor(s, 4, 16); s += __shfl_xor(s, 8, 16);
      const float mu = s * 0.0078125f;
      float vs = 0.0f;
      #pragma unroll
      for (int cc = 0; cc < 8; ++cc) { float d = xr[cc]-mu; vs = fmaf(d, d, vs); }
      vs += __shfl_xor(vs, 1, 16); vs += __shfl_xor(vs, 2, 16);
      vs += __shfl_xor(vs, 4, 16); vs += __shfl_xor(vs, 8, 16);
      const float rstd = 1.0f / sqrtf(vs * 0.0078125f + C_LNEPS);
      float4 o0, o1;
      o0.x = (xr[0]-mu)*rstd*gv[0] + bv[0];
      o0.y = (xr[1]-mu)*rstd*gv[1] + bv[1];
      o0.z = (xr[2]-mu)*rstd*gv[2] + bv[2];
      o0.w = (xr[3]-mu)*rstd*gv[3] + bv[3];
      o1.x = (xr[4]-mu)*rstd*gv[4] + bv[4];
      o1.y = (xr[5]-mu)*rstd*gv[5] + bv[5];
      o1.z = (xr[6]-mu)*rstd*gv[6] + bv[6];
      o1.w = (xr[7]-mu)*rstd*gv[7] + bv[7];
      *(float4*)(hs + row) = o0;
      *(float4*)(hs + row + 4) = o1;
    }
  }
  __syncthreads();

  // ---- keys = hn @ kp
  {
    float ky[8][8] = {};
    for (int kt = 0; kt < 2; ++kt) {
      for (int u = tid; u < 64*32; u += 256) {
        const int k = u >> 5, q = u & 31;
        *(float4*)(wt + k*W2P + q*4) =
            *(const float4*)(kp + (long long)(kt*64 + k)*128 + q*4);
      }
      __syncthreads();
      #pragma unroll 2
      for (int k4 = 0; k4 < 16; ++k4) {
        float wr[4][8];
        #pragma unroll
        for (int d = 0; d < 4; ++d) {
          float4 u0 = *(const float4*)(wt + (k4*4 + d)*W2P + ig*8);
          float4 u1 = *(const float4*)(wt + (k4*4 + d)*W2P + ig*8 + 4);
          wr[d][0]=u0.x; wr[d][1]=u0.y; wr[d][2]=u0.z; wr[d][3]=u0.w;
          wr[d][4]=u1.x; wr[d][5]=u1.y; wr[d][6]=u1.z; wr[d][7]=u1.w;
        }
        #pragma unroll
        for (int r = 0; r < 8; ++r) {
          float4 hv = *(const float4*)(hs + (tg + 16*r)*HSP + kt*64 + k4*4);
          #pragma unroll
          for (int cc = 0; cc < 8; ++cc) {
            ky[r][cc] = fmaf(hv.x, wr[0][cc], ky[r][cc]);
            ky[r][cc] = fmaf(hv.y, wr[1][cc], ky[r][cc]);
            ky[r][cc] = fmaf(hv.z, wr[2][cc], ky[r][cc]);
            ky[r][cc] = fmaf(hv.w, wr[3][cc], ky[r][cc]);
          }
        }
      }
      __syncthreads();
    }
    #pragma unroll
    for (int r = 0; r < 8; ++r) {
      const long long g = tokBase + tg + 16*r;
      float4 o0, o1;
      o0.x = ky[r][0]; o0.y = ky[r][1]; o0.z = ky[r][2]; o0.w = ky[r][3];
      o1.x = ky[r][4]; o1.y = ky[r][5]; o1.z = ky[r][6]; o1.w = ky[r][7];
      *(float4*)(keys + g*HD + ig*8) = o0;
      *(float4*)(keys + g*HD + ig*8 + 4) = o1;
    }
  }
}

// ---------------------------------------------------------------------------
// K3: the sequential scan. One block per batch, 512 threads, M in LDS.
// Chunked (Tc=64): Praw = kf@M^T, Graw = kf@kf^T (MFMA-able later), then a
// 64-step triangular recurrence, then rank-Tc update M += 0.05 * W2^T @ kf.
// Scaling trick: W2[s] = fire*err*inv_s, so vp_t = inv_t*(Praw[t] + .05*sum).
// Chunks 0..13 (t<=895) skipped: th(t)>1+2^-23 for t<=930 => provably no fire
// while M==0 (first fire at t=931, margin 2.9e-4 >> f32 noise).
// Dynamic LDS = 155424 B.
// ---------------------------------------------------------------------------
extern "C" __global__ __launch_bounds__(512, 1)
void k_scan(const float* __restrict__ keys, float* __restrict__ Mg)
{
  extern __shared__ float sm[];
  float* Msh = sm;              // [128][132]
  float* kf  = Msh + 128*132;   // [64][132] raw k chunk
  float* PW  = kf + 64*132;     // [64][132] Praw rows -> W2 rows
  float* G   = PW + 64*132;     // [64][68]  raw Gram
  float* nrm = G + 64*68;       // [64]
  float* inv = nrm + 64;        // [64]
  float* th  = inv + 64;        // [64]
  float* part = th + 64;        // [4][128]
  float* red  = part + 512;     // [2]

  const int tid = threadIdx.x;
  const int b = blockIdx.x;
  const float* kb = keys + (long long)b * LD * HD;

  for (int u = tid; u < 128*132; u += 512) Msh[u] = 0.0f;
  __syncthreads();

  for (int c = 14; c < 32; ++c) {
    const int t0 = c * 64;
    const int steps = (NSTEP - t0 < 64) ? (NSTEP - t0) : 64;

    for (int u = tid; u < steps*32; u += 512) {
      const int tt = u >> 5, seg = u & 31;
      *(float4*)(kf + tt*132 + seg*4) =
          *(const float4*)(kb + (long long)(t0 + tt)*HD + seg*4);
    }
    __syncthreads();

    // norms, inv-norms, thresholds (8 lanes per token)
    {
      const int tok = tid >> 3, pp = tid & 7;
      if (tok < steps) {
        float ss = 0.0f;
        #pragma unroll
        for (int q = 0; q < 4; ++q) {
          float4 v = *(const float4*)(kf + tok*132 + pp*16 + q*4);
          ss = fmaf(v.x, v.x, ss); ss = fmaf(v.y, v.y, ss);
          ss = fmaf(v.z, v.z, ss); ss = fmaf(v.w, v.w, ss);
        }
        ss += __shfl_xor(ss, 1, 8); ss += __shfl_xor(ss, 2, 8); ss += __shfl_xor(ss, 4, 8);
        if (pp == 0) {
          const float n = sqrtf(ss);
          nrm[tok] = n;
          inv[tok] = 1.0f / fmaxf(n, C_NEPS);
          th[tok]  = C_THMIN + C_THSPAN * (1.0f - (float)(t0 + tok) / 2047.0f);
        }
      }
    }
    __syncthreads();

    // P: Praw[t][i] = sum_j Msh[i][j]*kf[t][j]   (thread = 4t x 4i, strided t)
    {
      const int ti = tid & 15;
      const int ii = tid >> 4;  // 0..31
      float acc[4][4] = {};
      for (int j4 = 0; j4 < 32; ++j4) {
        float4 kv[4], mv[4];
        #pragma unroll
        for (int r = 0; r < 4; ++r)
          kv[r] = *(const float4*)(kf + (ti + 16*r)*132 + j4*4);
        #pragma unroll
        for (int cc = 0; cc < 4; ++cc)
          mv[cc] = *(const float4*)(Msh + (ii*4 + cc)*132 + j4*4);
        #pragma unroll
        for (int r = 0; r < 4; ++r)
          #pragma unroll
          for (int cc = 0; cc < 4; ++cc) {
            acc[r][cc] = fmaf(kv[r].x, mv[cc].x, acc[r][cc]);
            acc[r][cc] = fmaf(kv[r].y, mv[cc].y, acc[r][cc]);
            acc[r][cc] = fmaf(kv[r].z, mv[cc].z, acc[r][cc]);
            acc[r][cc] = fmaf(kv[r].w, mv[cc].w, acc[r][cc]);
          }
      }
      #pragma unroll
      for (int r = 0; r < 4; ++r) {
        float4 o; o.x = acc[r][0]; o.y = acc[r][1]; o.z = acc[r][2]; o.w = acc[r][3];
        *(float4*)(PW + (ti + 16*r)*132 + ii*4) = o;
      }
    }
    // G: Graw[s][t] = kf[s].kf[t]  (first 256 threads, 4s x 4t strided)
    if (tid < 256) {
      const int si = tid & 15;
      const int tj = tid >> 4;  // 0..15
      float acc[4][4] = {};
      for (int j4 = 0; j4 < 32; ++j4) {
        float4 sv[4], tv[4];
        #pragma unroll
        for (int r = 0; r < 4; ++r)
          sv[r] = *(const float4*)(kf + (si + 16*r)*132 + j4*4);
        #pragma unroll
        for (int cc = 0; cc < 4; ++cc)
          tv[cc] = *(const float4*)(kf + (tj + 16*cc)*132 + j4*4);
        #pragma unroll
        for (int r = 0; r < 4; ++r)
          #pragma unroll
          for (int cc = 0; cc < 4; ++cc) {
            acc[r][cc] = fmaf(sv[r].x, tv[cc].x, acc[r][cc]);
            acc[r][cc] = fmaf(sv[r].y, tv[cc].y, acc[r][cc]);
            acc[r][cc] = fmaf(sv[r].z, tv[cc].z, acc[r][cc]);
            acc[r][cc] = fmaf(sv[r].w, tv[cc].w, acc[r][cc]);
          }
      }
      #pragma unroll
      for (int r = 0; r < 4; ++r)
        #pragma unroll
        for (int cc = 0; cc < 4; ++cc)
          G[(si + 16*r)*68 + tj + 16*cc] = acc[r][cc];
    }
    __syncthreads();

    // sequential triangular recurrence
    for (int t = 0; t < steps; ++t) {
      const int q = tid >> 7, h = tid & 127;
      {
        float p = 0.0f;
        const int s0 = q*16;
        const int s1 = (t < s0+16) ? t : (s0+16);
        for (int s = s0; s < s1; ++s)
          p = fmaf(PW[s*132 + h], G[s*68 + t], p);
        part[q*128 + h] = p;
      }
      __syncthreads();
      float err = 0.0f;
      if (tid < 128) {
        const float ssum = part[h] + part[128 + h] + part[256 + h] + part[384 + h];
        const float vp = inv[t] * fmaf(C_ALPHA, ssum, PW[t*132 + h]);
        err = kf[t*132 + h] - vp;
        float e2 = err * err;
        e2 += __shfl_xor(e2, 32); e2 += __shfl_xor(e2, 16);
        e2 += __shfl_xor(e2, 8);  e2 += __shfl_xor(e2, 4);
        e2 += __shfl_xor(e2, 2);  e2 += __shfl_xor(e2, 1);
        if ((tid & 63) == 0) red[tid >> 6] = e2;
      }
      __syncthreads();
      const float en = sqrtf(red[0] + red[1]);
      const bool fire = (en >= th[t] * nrm[t]);
      if (tid < 128) PW[t*132 + h] = fire ? err * inv[t] : 0.0f;
      __syncthreads();
    }

    // U: Msh[i][j] += 0.05 * sum_s W2[s][i]*kf[s][j]  (thread = 4i x 8j)
    {
      const int im = tid & 31;
      const int jm = tid >> 5;  // 0..15
      float acc[4][8] = {};
      for (int s = 0; s < steps; ++s) {
        float wv[4];
        #pragma unroll
        for (int r = 0; r < 4; ++r) wv[r] = PW[s*132 + im + 32*r];
        const float4 k0 = *(const float4*)(kf + s*132 + jm*8);
        const float4 k1 = *(const float4*)(kf + s*132 + jm*8 + 4);
        #pragma unroll
        for (int r = 0; r < 4; ++r) {
          acc[r][0] = fmaf(wv[r], k0.x, acc[r][0]);
          acc[r][1] = fmaf(wv[r], k0.y, acc[r][1]);
          acc[r][2] = fmaf(wv[r], k0.z, acc[r][2]);
          acc[r][3] = fmaf(wv[r], k0.w, acc[r][3]);
          acc[r][4] = fmaf(wv[r], k1.x, acc[r][4]);
          acc[r][5] = fmaf(wv[r], k1.y, acc[r][5]);
          acc[r][6] = fmaf(wv[r], k1.z, acc[r][6]);
          acc[r][7] = fmaf(wv[r], k1.w, acc[r][7]);
        }
      }
      #pragma unroll
      for (int r = 0; r < 4; ++r) {
        float* mrow = Msh + (im + 32*r)*132 + jm*8;
        #pragma unroll
        for (int jj = 0; jj < 8; ++jj)
          mrow[jj] = fmaf(C_ALPHA, acc[r][jj], mrow[jj]);
      }
    }
    __syncthreads();
  }

  for (int u = tid; u < 128*32; u += 512) {
    const int i = u >> 5, q = u & 31;
    *(float4*)(Mg + (long long)b*16384 + i*128 + q*4) =
        *(const float4*)(Msh + i*132 + q*4);
  }
}

// ---------------------------------------------------------------------------
// K4a: read = M @ q ; rr = read @ rp_w + rp_b     (64 blocks x 128 threads)
// ---------------------------------------------------------------------------
extern "C" __global__ __launch_bounds__(128, 1)
void k_read(const float* __restrict__ keys, const float* __restrict__ Mg,
            const float* __restrict__ rpw, const float* __restrict__ rpb,
            float* __restrict__ rr)
{
  __shared__ float qv[128];
  __shared__ float rd[128];
  const int b = blockIdx.x, tid = threadIdx.x;
  qv[tid] = keys[((long long)b*LD + (LD-1))*HD + tid];
  __syncthreads();
  float acc = 0.0f;
  const float* Mrow = Mg + (long long)b*16384 + (long long)tid*128;
  for (int j4 = 0; j4 < 32; ++j4) {
    float4 m = *(const float4*)(Mrow + j4*4);
    acc = fmaf(m.x, qv[j4*4+0], acc);
    acc = fmaf(m.y, qv[j4*4+1], acc);
    acc = fmaf(m.z, qv[j4*4+2], acc);
    acc = fmaf(m.w, qv[j4*4+3], acc);
  }
  rd[tid] = acc;
  __syncthreads();
  float a2 = rpb[tid];
  for (int k = 0; k < 128; ++k) a2 = fmaf(rd[k], rpw[k*128 + tid], a2);
  rr[b*128 + tid] = a2;
}

// ---------------------------------------------------------------------------
// K4b: out[b][v] = rr[b] . out_w[:,v] + out_b[v]   (250 blocks x 256 threads)
// ---------------------------------------------------------------------------
extern "C" __global__ __launch_bounds__(256, 1)
void k_out(const float* __restrict__ rr, const float* __restrict__ outw,
           const float* __restrict__ outb, float* __restrict__ out)
{
  __shared__ float rl[64*128];
  const int tid = threadIdx.x;
  for (int u = tid; u < 8192; u += 256) rl[u] = rr[u];
  __syncthreads();
  const int v = blockIdx.x*128 + (tid & 127);
  const int bg = tid >> 7;   // 0..1 -> batches bg*32..+31
  const float ob = outb[v];
  float acc[32];
  #pragma unroll
  for (int bb = 0; bb < 32; ++bb) acc[bb] = 0.0f;
  for (int h = 0; h < 128; ++h) {
    const float wv = outw[(long long)h*VD + v];
    #pragma unroll
    for (int bb = 0; bb < 32; ++bb)
      acc[bb] = fmaf(rl[(bg*32 + bb)*128 + h], wv, acc[bb]);
  }
  #pragma unroll
  for (int bb = 0; bb < 32; ++bb)
    out[(long long)(bg*32 + bb)*VD + v] = acc[bb] + ob;
}

// ---------------------------------------------------------------------------
extern "C" void kernel_launch(void* const* d_in, const int* in_sizes, int n_in,
                              void* d_out, int out_size, void* d_ws, size_t ws_size,
                              hipStream_t stream)
{
  const int*   seq   = (const int*)d_in[0];
  const float* embed = (const float*)d_in[1];
  const float* w1    = (const float*)d_in[2];
  const float* b1    = (const float*)d_in[3];
  const float* w2    = (const float*)d_in[4];
  const float* b2    = (const float*)d_in[5];
  const float* ln_g  = (const float*)d_in[6];
  const float* ln_b  = (const float*)d_in[7];
  const float* kp_w  = (const float*)d_in[8];
  const float* rp_w  = (const float*)d_in[9];
  const float* rp_b  = (const float*)d_in[10];
  const float* out_w = (const float*)d_in[11];
  const float* out_b = (const float*)d_in[12];
  float* out = (float*)d_out;

  char* ws = (char*)d_ws;
  float* keys = (float*)ws;                               // 64*2048*128 f32 = 64 MiB
  float* Mg   = (float*)(ws + 67108864);                  // 64*128*128 f32 = 4 MiB
  float* rr   = (float*)(ws + 67108864 + 4194304);        // 64*128 f32

  hipLaunchKernelGGL(k_tokens, dim3(1024), dim3(256), 137216, stream,
                     seq, embed, w1, b1, w2, b2, ln_g, ln_b, kp_w, keys);
  hipLaunchKernelGGL(k_scan, dim3(64), dim3(512), 155424, stream, keys, Mg);
  hipLaunchKernelGGL(k_read, dim3(64), dim3(128), 0, stream, keys, Mg, rp_w, rp_b, rr);
  hipLaunchKernelGGL(k_out, dim3(250), dim3(256), 0, stream, rr, out_w, out_b, out);
}

// Round 2
// 1322.125 us; speedup vs baseline: 1.6995x; 1.6995x over previous
//
#include <hip/hip_runtime.h>

#define HD 128
#define LD 2048
#define BD 64
#define VD 32000
#define NSTEP 2047   // L-1 scan steps, t = 0..2046

// f32 constants exactly matching the reference's f32-cast scalars
#define C_ALPHA  0.05f    // (1.0 - 0.95) rounded to f32
#define C_THMIN  0.4f
#define C_THSPAN 1.1f     // (1.5 - 0.4) rounded to f32
#define C_NEPS   1e-12f
#define C_LNEPS  1e-5f

// ---------------------------------------------------------------------------
// K1: fused embed-gather + MLP (h@w1,relu,@w2,+h,+b2) + LayerNorm + keys=hn@kp
// Only tokens >= 896 are live (first possible fire is t=931: th(930)=1.000244>1,
// so steps t<931 are provably no-ops while M==0; the scan starts at t=928 and
// never reads keys rows < 928; k_read reads row 2047).
// 128 tokens per block, 256 threads, 9 blocks per batch (tokens 896..2047).
// ---------------------------------------------------------------------------
#define HSP 132   // h / hn tile pitch   [128][132]
#define W1P 68    // w1 tile pitch       [128][68]
#define W2P 132   // w2 / kp tile pitch  [64][132]
#define ATP 68    // a tile pitch        [128][68]
#define TOK0 896
#define TBLK 9    // blocks per batch: (2048-896)/128

extern "C" __global__ __launch_bounds__(256, 1)
void k_tokens(const int* __restrict__ seq, const float* __restrict__ embed,
              const float* __restrict__ w1, const float* __restrict__ b1,
              const float* __restrict__ w2, const float* __restrict__ b2,
              const float* __restrict__ lng, const float* __restrict__ lnb,
              const float* __restrict__ kp, float* __restrict__ keys)
{
  extern __shared__ float sm[];
  float* hs = sm;                 // [128][HSP]  h, later hn
  float* wt = sm + 128*HSP;       // [128][W1P] (w1 tile) or [64][W2P] (w2/kp)
  float* at = wt + 128*W1P;       // [128][ATP]  relu tile
  const int tid = threadIdx.x;
  const int bb  = blockIdx.x / TBLK;
  const int rel = blockIdx.x % TBLK;
  const long long tokBase = (long long)bb * LD + TOK0 + rel * 128;

  // ---- gather h = embed[seq]
  for (int u = tid; u < 128*32; u += 256) {
    const int tok = u >> 5, seg = u & 31;
    const int s = seq[tokBase + tok];
    *(float4*)(hs + tok*HSP + seg*4) =
        *(const float4*)(embed + (long long)s*HD + seg*4);
  }
  __syncthreads();

  const int tg = tid >> 4;   // token group: tok = tg + 16*r, r=0..7
  const int ig = tid & 15;   // column group

  float xacc[8][8] = {};     // x (MLP out) accumulator: 8 tok x 8 i

  for (int jt = 0; jt < 4; ++jt) {
    // stage w1 tile [128 i][64 j]
    for (int u = tid; u < 128*16; u += 256) {
      const int i = u >> 4, q = u & 15;
      *(float4*)(wt + i*W1P + q*4) =
          *(const float4*)(w1 + (long long)i*256 + jt*64 + q*4);
    }
    __syncthreads();
    // a-tile = relu(h @ w1tile + b1): thread = 8 tok x 4 j
    {
      float aa[8][4];
      float b1v[4];
      #pragma unroll
      for (int c = 0; c < 4; ++c) b1v[c] = b1[jt*64 + ig*4 + c];
      #pragma unroll
      for (int r = 0; r < 8; ++r)
        #pragma unroll
        for (int c = 0; c < 4; ++c) aa[r][c] = b1v[c];
      #pragma unroll 4
      for (int i4 = 0; i4 < 32; ++i4) {
        float wc[4][4];
        #pragma unroll
        for (int d = 0; d < 4; ++d) {
          float4 u = *(const float4*)(wt + (i4*4 + d)*W1P + ig*4);
          wc[d][0] = u.x; wc[d][1] = u.y; wc[d][2] = u.z; wc[d][3] = u.w;
        }
        #pragma unroll
        for (int r = 0; r < 8; ++r) {
          float4 hv = *(const float4*)(hs + (tg + 16*r)*HSP + i4*4);
          #pragma unroll
          for (int c = 0; c < 4; ++c) {
            aa[r][c] = fmaf(hv.x, wc[0][c], aa[r][c]);
            aa[r][c] = fmaf(hv.y, wc[1][c], aa[r][c]);
            aa[r][c] = fmaf(hv.z, wc[2][c], aa[r][c]);
            aa[r][c] = fmaf(hv.w, wc[3][c], aa[r][c]);
          }
        }
      }
      #pragma unroll
      for (int r = 0; r < 8; ++r) {
        float4 o;
        o.x = fmaxf(aa[r][0], 0.0f); o.y = fmaxf(aa[r][1], 0.0f);
        o.z = fmaxf(aa[r][2], 0.0f); o.w = fmaxf(aa[r][3], 0.0f);
        *(float4*)(at + (tg + 16*r)*ATP + ig*4) = o;
      }
    }
    __syncthreads();
    // stage w2 tile [64 k][128 i] (overwrites w1 tile)
    for (int u = tid; u < 64*32; u += 256) {
      const int k = u >> 5, q = u & 31;
      *(float4*)(wt + k*W2P + q*4) =
          *(const float4*)(w2 + (long long)(jt*64 + k)*128 + q*4);
    }
    __syncthreads();
    // x += a-tile @ w2tile: thread = 8 tok x 8 i
    #pragma unroll 2
    for (int k4 = 0; k4 < 16; ++k4) {
      float wr[4][8];
      #pragma unroll
      for (int d = 0; d < 4; ++d) {
        float4 u0 = *(const float4*)(wt + (k4*4 + d)*W2P + ig*8);
        float4 u1 = *(const float4*)(wt + (k4*4 + d)*W2P + ig*8 + 4);
        wr[d][0]=u0.x; wr[d][1]=u0.y; wr[d][2]=u0.z; wr[d][3]=u0.w;
        wr[d][4]=u1.x; wr[d][5]=u1.y; wr[d][6]=u1.z; wr[d][7]=u1.w;
      }
      #pragma unroll
      for (int r = 0; r < 8; ++r) {
        float4 av = *(const float4*)(at + (tg + 16*r)*ATP + k4*4);
        #pragma unroll
        for (int cc = 0; cc < 8; ++cc) {
          xacc[r][cc] = fmaf(av.x, wr[0][cc], xacc[r][cc]);
          xacc[r][cc] = fmaf(av.y, wr[1][cc], xacc[r][cc]);
          xacc[r][cc] = fmaf(av.z, wr[2][cc], xacc[r][cc]);
          xacc[r][cc] = fmaf(av.w, wr[3][cc], xacc[r][cc]);
        }
      }
    }
    __syncthreads();
  }

  // ---- x = h + (x + b2); LayerNorm over i (16 lanes share a token); hn -> hs
  {
    float b2v[8], gv[8], bv[8];
    #pragma unroll
    for (int cc = 0; cc < 8; ++cc) {
      b2v[cc] = b2[ig*8 + cc]; gv[cc] = lng[ig*8 + cc]; bv[cc] = lnb[ig*8 + cc];
    }
    #pragma unroll
    for (int r = 0; r < 8; ++r) {
      const int row = (tg + 16*r)*HSP + ig*8;
      float4 h0 = *(const float4*)(hs + row);
      float4 h1 = *(const float4*)(hs + row + 4);
      float xr[8];
      xr[0] = h0.x + (xacc[r][0] + b2v[0]);
      xr[1] = h0.y + (xacc[r][1] + b2v[1]);
      xr[2] = h0.z + (xacc[r][2] + b2v[2]);
      xr[3] = h0.w + (xacc[r][3] + b2v[3]);
      xr[4] = h1.x + (xacc[r][4] + b2v[4]);
      xr[5] = h1.y + (xacc[r][5] + b2v[5]);
      xr[6] = h1.z + (xacc[r][6] + b2v[6]);
      xr[7] = h1.w + (xacc[r][7] + b2v[7]);
      float s = xr[0]+xr[1]+xr[2]+xr[3]+xr[4]+xr[5]+xr[6]+xr[7];
      s += __shfl_xor(s, 1, 16); s += __shfl_xor(s, 2, 16);
      s += __shfl_xor(s, 4, 16); s += __shfl_xor(s, 8, 16);
      const float mu = s * 0.0078125f;
      float vs = 0.0f;
      #pragma unroll
      for (int cc = 0; cc < 8; ++cc) { float d = xr[cc]-mu; vs = fmaf(d, d, vs); }
      vs += __shfl_xor(vs, 1, 16); vs += __shfl_xor(vs, 2, 16);
      vs += __shfl_xor(vs, 4, 16); vs += __shfl_xor(vs, 8, 16);
      const float rstd = 1.0f / sqrtf(vs * 0.0078125f + C_LNEPS);
      float4 o0, o1;
      o0.x = (xr[0]-mu)*rstd*gv[0] + bv[0];
      o0.y = (xr[1]-mu)*rstd*gv[1] + bv[1];
      o0.z = (xr[2]-mu)*rstd*gv[2] + bv[2];
      o0.w = (xr[3]-mu)*rstd*gv[3] + bv[3];
      o1.x = (xr[4]-mu)*rstd*gv[4] + bv[4];
      o1.y = (xr[5]-mu)*rstd*gv[5] + bv[5];
      o1.z = (xr[6]-mu)*rstd*gv[6] + bv[6];
      o1.w = (xr[7]-mu)*rstd*gv[7] + bv[7];
      *(float4*)(hs + row) = o0;
      *(float4*)(hs + row + 4) = o1;
    }
  }
  __syncthreads();

  // ---- keys = hn @ kp
  {
    float ky[8][8] = {};
    for (int kt = 0; kt < 2; ++kt) {
      for (int u = tid; u < 64*32; u += 256) {
        const int k = u >> 5, q = u & 31;
        *(float4*)(wt + k*W2P + q*4) =
            *(const float4*)(kp + (long long)(kt*64 + k)*128 + q*4);
      }
      __syncthreads();
      #pragma unroll 2
      for (int k4 = 0; k4 < 16; ++k4) {
        float wr[4][8];
        #pragma unroll
        for (int d = 0; d < 4; ++d) {
          float4 u0 = *(const float4*)(wt + (k4*4 + d)*W2P + ig*8);
          float4 u1 = *(const float4*)(wt + (k4*4 + d)*W2P + ig*8 + 4);
          wr[d][0]=u0.x; wr[d][1]=u0.y; wr[d][2]=u0.z; wr[d][3]=u0.w;
          wr[d][4]=u1.x; wr[d][5]=u1.y; wr[d][6]=u1.z; wr[d][7]=u1.w;
        }
        #pragma unroll
        for (int r = 0; r < 8; ++r) {
          float4 hv = *(const float4*)(hs + (tg + 16*r)*HSP + kt*64 + k4*4);
          #pragma unroll
          for (int cc = 0; cc < 8; ++cc) {
            ky[r][cc] = fmaf(hv.x, wr[0][cc], ky[r][cc]);
            ky[r][cc] = fmaf(hv.y, wr[1][cc], ky[r][cc]);
            ky[r][cc] = fmaf(hv.z, wr[2][cc], ky[r][cc]);
            ky[r][cc] = fmaf(hv.w, wr[3][cc], ky[r][cc]);
          }
        }
      }
      __syncthreads();
    }
    #pragma unroll
    for (int r = 0; r < 8; ++r) {
      const long long g = tokBase + tg + 16*r;
      float4 o0, o1;
      o0.x = ky[r][0]; o0.y = ky[r][1]; o0.z = ky[r][2]; o0.w = ky[r][3];
      o1.x = ky[r][4]; o1.y = ky[r][5]; o1.z = ky[r][6]; o1.w = ky[r][7];
      *(float4*)(keys + g*HD + ig*8) = o0;
      *(float4*)(keys + g*HD + ig*8 + 4) = o1;
    }
  }
}

// ---------------------------------------------------------------------------
// K3: the scan, software-pipelined. One block per batch, 512 threads (8 waves).
// Chunk Tc=32 over t. Per chunk c, per stage:
//   stage2 (all waves): load kf_{c+1}->LDS; P-waves: fixup P_c = P_pre_c +
//     0.05*Gx^T@W2_{c-1} (exact: P_c = kf_c@M_{c-1}^T), write P; all: U:
//     M += 0.05*W2_{c-1}^T@kf_{c-1} (kf from global, wave-broadcast loads).
//   stage3: wave0 runs the 32-step recurrence ENTIRELY IN-WAVE (no barriers:
//     acc[32] float2 in VGPRs, __shfl_xor norm reduce, G broadcast reads);
//     waves 1,2,3,5 compute P_pre_{c+1}=kf_{c+1}@M_{c-1}^T into registers;
//     wave4 computes norms/inv/th; wave6: G_{c+1}; wave7: Gx_{c->c+1}.
// 2 barriers per chunk (vs ~192 before). Chunks 0..28 skipped (t<928: no fire
// possible, M stays 0: th(930)=1.000244 > 1, margin 2.4e-4 >> f32 noise).
// Dynamic LDS = 148608 B.
// ---------------------------------------------------------------------------
#define KFP 132   // kf/P/W2/M pitch
#define GP  33    // G/Gx pitch
#define C0  29    // first chunk (t0 = 928)

extern "C" __global__ __launch_bounds__(512, 1)
void k_scan(const float* __restrict__ keys, float* __restrict__ Mg)
{
  extern __shared__ float sm[];
  float* Msh  = sm;                    // [128][132]
  float* kbuf = sm + 16896;            // [2][32][132]
  float* Pl   = sm + 25344;            // [32][132]
  float* W2l  = sm + 29568;            // [32][132]
  float* Gb   = sm + 33792;            // [2][32][33]
  float* Gxl  = sm + 35904;            // [32][33]
  float* nrmb = sm + 36960;            // [2][32]
  float* invb = sm + 37024;            // [2][32]
  float* thb  = sm + 37088;            // [2][32]

  const int tid  = threadIdx.x;
  const int lane = tid & 63;
  const int wv   = tid >> 6;
  const int b    = blockIdx.x;
  const float* kb = keys + (long long)b * LD * HD;

  const bool isP = (wv==1) || (wv==2) || (wv==3) || (wv==5);
  const int pidx = (wv==5) ? 3 : (wv-1);            // 0..3 for P waves
  const int tb   = (pidx*2 + (lane>>5)) * 4;        // t' base (0..28 step 4)
  const int ib   = lane & 31;                        // i base (i = ib+32r)
  float pacc[4][4] = {};                             // P_pre tile (t' x i)

  // ---------------- prologue ----------------
  for (int u = tid; u < 128*KFP; u += 512) Msh[u] = 0.0f;
  // load kf chunk C0 into kbuf[1]  (C0&1 == 1)
  for (int u = tid; u < 1024; u += 512) {
    const int tt = u >> 5, seg = u & 31;
    *(float4*)(kbuf + KFP*32 + tt*KFP + seg*4) =
        *(const float4*)(kb + (long long)(C0*32 + tt)*HD + seg*4);
  }
  __syncthreads();
  // norms/inv/th for chunk C0 (first 256 threads, 8 lanes per token)
  if (tid < 256) {
    const int tok = tid >> 3, pp = tid & 7;
    float ss = 0.0f;
    #pragma unroll
    for (int q = 0; q < 4; ++q) {
      float4 v = *(const float4*)(kbuf + KFP*32 + tok*KFP + pp*16 + q*4);
      ss = fmaf(v.x,v.x,ss); ss = fmaf(v.y,v.y,ss);
      ss = fmaf(v.z,v.z,ss); ss = fmaf(v.w,v.w,ss);
    }
    ss += __shfl_xor(ss,1,8); ss += __shfl_xor(ss,2,8); ss += __shfl_xor(ss,4,8);
    if (pp == 0) {
      const float n = sqrtf(ss);
      nrmb[32 + tok] = n;
      invb[32 + tok] = 1.0f / fmaxf(n, C_NEPS);
      thb [32 + tok] = C_THMIN + C_THSPAN * (1.0f - (float)(C0*32 + tok) / 2047.0f);
    }
  }
  // G for chunk C0 (all threads, 2 outputs each)
  for (int u = tid; u < 1024; u += 512) {
    const int s = u >> 5, t = u & 31;
    float a = 0.0f;
    for (int j4 = 0; j4 < 32; ++j4) {
      float4 sv = *(const float4*)(kbuf + KFP*32 + s*KFP + j4*4);
      float4 tv = *(const float4*)(kbuf + KFP*32 + t*KFP + j4*4);
      a = fmaf(sv.x,tv.x,a); a = fmaf(sv.y,tv.y,a);
      a = fmaf(sv.z,tv.z,a); a = fmaf(sv.w,tv.w,a);
    }
    Gb[GP*32 + s*GP + t] = a;
  }
  __syncthreads();

  // ---------------- main loop ----------------
  for (int c = C0; c <= 64; ++c) {
    const int cur = c & 1, nxt = cur ^ 1;
    const int t0 = c * 32;

    // ===== stage 2 =====
    if (c < 63) {   // load kf_{c+1} into kbuf[nxt]
      for (int u = tid; u < 1024; u += 512) {
        const int tt = u >> 5, seg = u & 31;
        *(float4*)(kbuf + nxt*32*KFP + tt*KFP + seg*4) =
            *(const float4*)(kb + (long long)(t0 + 32 + tt)*HD + seg*4);
      }
    }
    if (isP && c <= 63) {
      if (c > C0) {   // fixup: pacc += 0.05 * sum_s W2[s][i]*Gx[s][t']
        #pragma unroll 4
        for (int s = 0; s < 32; ++s) {
          float gx[4], wr[4];
          #pragma unroll
          for (int ss = 0; ss < 4; ++ss) gx[ss] = Gxl[s*GP + tb + ss];
          #pragma unroll
          for (int r = 0; r < 4; ++r) wr[r] = W2l[s*KFP + ib + 32*r];
          #pragma unroll
          for (int ss = 0; ss < 4; ++ss)
            #pragma unroll
            for (int r = 0; r < 4; ++r)
              pacc[ss][r] = fmaf(C_ALPHA * wr[r], gx[ss], pacc[ss][r]);
        }
      }
      #pragma unroll
      for (int ss = 0; ss < 4; ++ss)
        #pragma unroll
        for (int r = 0; r < 4; ++r)
          Pl[(tb+ss)*KFP + ib + 32*r] = pacc[ss][r];
    }
    if (c > C0) {   // U: M += 0.05 * W2_{c-1}^T @ kf_{c-1}  (kf from global)
      const float* kg = kb + (long long)(t0 - 32)*HD;
      const int i = tid & 127, jb = tid >> 7;
      float uacc[32] = {};
      for (int s = 0; s < 32; ++s) {
        const float w = W2l[s*KFP + i];
        #pragma unroll
        for (int q = 0; q < 8; ++q) {
          float4 kv = *(const float4*)(kg + s*HD + jb*32 + q*4);
          uacc[q*4+0] = fmaf(w, kv.x, uacc[q*4+0]);
          uacc[q*4+1] = fmaf(w, kv.y, uacc[q*4+1]);
          uacc[q*4+2] = fmaf(w, kv.z, uacc[q*4+2]);
          uacc[q*4+3] = fmaf(w, kv.w, uacc[q*4+3]);
        }
      }
      #pragma unroll
      for (int q = 0; q < 8; ++q) {
        float* mp = Msh + i*KFP + jb*32 + q*4;
        float4 m = *(float4*)mp;
        m.x = fmaf(C_ALPHA, uacc[q*4+0], m.x);
        m.y = fmaf(C_ALPHA, uacc[q*4+1], m.y);
        m.z = fmaf(C_ALPHA, uacc[q*4+2], m.z);
        m.w = fmaf(C_ALPHA, uacc[q*4+3], m.w);
        *(float4*)mp = m;
      }
    }
    __syncthreads();
    if (c == 64) break;   // epilogue U applied; M final

    // ===== stage 3 =====
    if (wv == 0) {
      // ---- in-wave recurrence for chunk c ----
      const float* kfc  = kbuf + cur*32*KFP;
      const float* Gc   = Gb   + cur*32*GP;
      const float* nrmc = nrmb + cur*32;
      const float* invc = invb + cur*32;
      const float* thc  = thb  + cur*32;
      const int l2 = lane*2;
      float2 acc[32];
      #pragma unroll
      for (int u = 0; u < 32; ++u) { acc[u].x = 0.0f; acc[u].y = 0.0f; }
      #pragma unroll
      for (int t = 0; t < 32; ++t) {
        const float2 p2 = *(const float2*)(Pl  + t*KFP + l2);
        const float2 k2 = *(const float2*)(kfc + t*KFP + l2);
        const float it  = invc[t];
        const float vx = it * fmaf(C_ALPHA, acc[t].x, p2.x);
        const float vy = it * fmaf(C_ALPHA, acc[t].y, p2.y);
        const float ex = k2.x - vx;
        const float ey = k2.y - vy;
        float e2 = fmaf(ex, ex, ey*ey);
        e2 += __shfl_xor(e2, 1);  e2 += __shfl_xor(e2, 2);
        e2 += __shfl_xor(e2, 4);  e2 += __shfl_xor(e2, 8);
        e2 += __shfl_xor(e2, 16); e2 += __shfl_xor(e2, 32);
        bool fire = (sqrtf(e2) >= thc[t] * nrmc[t]) && (t0 + t < NSTEP);
        const float wx = fire ? ex * it : 0.0f;
        const float wy = fire ? ey * it : 0.0f;
        float2 w2v; w2v.x = wx; w2v.y = wy;
        *(float2*)(W2l + t*KFP + l2) = w2v;
        const float* gr = Gc + t*GP;
        #pragma unroll
        for (int u = t+1; u < 32; ++u) {
          const float g = gr[u];
          acc[u].x = fmaf(wx, g, acc[u].x);
          acc[u].y = fmaf(wy, g, acc[u].y);
        }
      }
    } else if (c < 63) {
      const float* kfn = kbuf + nxt*32*KFP;
      if (isP) {
        // P_pre_{c+1} = kf_{c+1} @ M^T  (M = M_{c-1}) into registers
        #pragma unroll
        for (int ss = 0; ss < 4; ++ss)
          #pragma unroll
          for (int r = 0; r < 4; ++r) pacc[ss][r] = 0.0f;
        for (int j4 = 0; j4 < 32; ++j4) {
          float4 kv[4], mv[4];
          #pragma unroll
          for (int ss = 0; ss < 4; ++ss)
            kv[ss] = *(const float4*)(kfn + (tb+ss)*KFP + j4*4);
          #pragma unroll
          for (int r = 0; r < 4; ++r)
            mv[r] = *(const float4*)(Msh + (ib+32*r)*KFP + j4*4);
          #pragma unroll
          for (int ss = 0; ss < 4; ++ss)
            #pragma unroll
            for (int r = 0; r < 4; ++r) {
              pacc[ss][r] = fmaf(kv[ss].x, mv[r].x, pacc[ss][r]);
              pacc[ss][r] = fmaf(kv[ss].y, mv[r].y, pacc[ss][r]);
              pacc[ss][r] = fmaf(kv[ss].z, mv[r].z, pacc[ss][r]);
              pacc[ss][r] = fmaf(kv[ss].w, mv[r].w, pacc[ss][r]);
            }
        }
      } else if (wv == 4) {
        // norms/inv/th for chunk c+1 (2 lanes per token)
        const int tok = lane >> 1, hh = lane & 1;
        float ss = 0.0f;
        #pragma unroll
        for (int q = 0; q < 16; ++q) {
          float4 v = *(const float4*)(kfn + tok*KFP + hh*64 + q*4);
          ss = fmaf(v.x,v.x,ss); ss = fmaf(v.y,v.y,ss);
          ss = fmaf(v.z,v.z,ss); ss = fmaf(v.w,v.w,ss);
        }
        ss += __shfl_xor(ss, 1);
        if (hh == 0) {
          const float n = sqrtf(ss);
          nrmb[nxt*32 + tok] = n;
          invb[nxt*32 + tok] = 1.0f / fmaxf(n, C_NEPS);
          thb [nxt*32 + tok] = C_THMIN + C_THSPAN * (1.0f - (float)(t0 + 32 + tok) / 2047.0f);
        }
      } else if (wv == 6) {
        // G_{c+1}
        const int s = lane & 31, tq = (lane >> 5) * 16;
        float ga[16] = {};
        for (int j4 = 0; j4 < 32; ++j4) {
          float4 sv = *(const float4*)(kfn + s*KFP + j4*4);
          #pragma unroll
          for (int q = 0; q < 16; ++q) {
            float4 tv = *(const float4*)(kfn + (tq+q)*KFP + j4*4);
            ga[q] = fmaf(sv.x,tv.x,ga[q]); ga[q] = fmaf(sv.y,tv.y,ga[q]);
            ga[q] = fmaf(sv.z,tv.z,ga[q]); ga[q] = fmaf(sv.w,tv.w,ga[q]);
          }
        }
        #pragma unroll
        for (int q = 0; q < 16; ++q) Gb[nxt*32*GP + s*GP + tq + q] = ga[q];
      } else {
        // wv == 7: Gx[s][t'] = kf_c[s] . kf_{c+1}[t']
        const float* kfc = kbuf + cur*32*KFP;
        const int s = lane & 31, tq = (lane >> 5) * 16;
        float ga[16] = {};
        for (int j4 = 0; j4 < 32; ++j4) {
          float4 sv = *(const float4*)(kfc + s*KFP + j4*4);
          #pragma unroll
          for (int q = 0; q < 16; ++q) {
            float4 tv = *(const float4*)(kfn + (tq+q)*KFP + j4*4);
            ga[q] = fmaf(sv.x,tv.x,ga[q]); ga[q] = fmaf(sv.y,tv.y,ga[q]);
            ga[q] = fmaf(sv.z,tv.z,ga[q]); ga[q] = fmaf(sv.w,tv.w,ga[q]);
          }
        }
        #pragma unroll
        for (int q = 0; q < 16; ++q) Gxl[s*GP + tq + q] = ga[q];
      }
    }
    __syncthreads();
  }

  // store M
  for (int u = tid; u < 4096; u += 512) {
    const int i = u >> 5, q = u & 31;
    *(float4*)(Mg + (long long)b*16384 + i*128 + q*4) =
        *(const float4*)(Msh + i*KFP + q*4);
  }
}

// ---------------------------------------------------------------------------
// K4a: read = M @ q ; rr = read @ rp_w + rp_b     (64 blocks x 128 threads)
// ---------------------------------------------------------------------------
extern "C" __global__ __launch_bounds__(128, 1)
void k_read(const float* __restrict__ keys, const float* __restrict__ Mg,
            const float* __restrict__ rpw, const float* __restrict__ rpb,
            float* __restrict__ rr)
{
  __shared__ float qv[128];
  __shared__ float rd[128];
  const int b = blockIdx.x, tid = threadIdx.x;
  qv[tid] = keys[((long long)b*LD + (LD-1))*HD + tid];
  __syncthreads();
  float acc = 0.0f;
  const float* Mrow = Mg + (long long)b*16384 + (long long)tid*128;
  for (int j4 = 0; j4 < 32; ++j4) {
    float4 m = *(const float4*)(Mrow + j4*4);
    acc = fmaf(m.x, qv[j4*4+0], acc);
    acc = fmaf(m.y, qv[j4*4+1], acc);
    acc = fmaf(m.z, qv[j4*4+2], acc);
    acc = fmaf(m.w, qv[j4*4+3], acc);
  }
  rd[tid] = acc;
  __syncthreads();
  float a2 = rpb[tid];
  for (int k = 0; k < 128; ++k) a2 = fmaf(rd[k], rpw[k*128 + tid], a2);
  rr[b*128 + tid] = a2;
}

// ---------------------------------------------------------------------------
// K4b: out[b][v] = rr[b] . out_w[:,v] + out_b[v]   (250 blocks x 256 threads)
// ---------------------------------------------------------------------------
extern "C" __global__ __launch_bounds__(256, 1)
void k_out(const float* __restrict__ rr, const float* __restrict__ outw,
           const float* __restrict__ outb, float* __restrict__ out)
{
  __shared__ float rl[64*128];
  const int tid = threadIdx.x;
  for (int u = tid; u < 8192; u += 256) rl[u] = rr[u];
  __syncthreads();
  const int v = blockIdx.x*128 + (tid & 127);
  const int bg = tid >> 7;   // 0..1 -> batches bg*32..+31
  const float ob = outb[v];
  float acc[32];
  #pragma unroll
  for (int bb = 0; bb < 32; ++bb) acc[bb] = 0.0f;
  for (int h = 0; h < 128; ++h) {
    const float wv = outw[(long long)h*VD + v];
    #pragma unroll
    for (int bb = 0; bb < 32; ++bb)
      acc[bb] = fmaf(rl[(bg*32 + bb)*128 + h], wv, acc[bb]);
  }
  #pragma unroll
  for (int bb = 0; bb < 32; ++bb)
    out[(long long)(bg*32 + bb)*VD + v] = acc[bb] + ob;
}

// ---------------------------------------------------------------------------
extern "C" void kernel_launch(void* const* d_in, const int* in_sizes, int n_in,
                              void* d_out, int out_size, void* d_ws, size_t ws_size,
                              hipStream_t stream)
{
  const int*   seq   = (const int*)d_in[0];
  const float* embed = (const float*)d_in[1];
  const float* w1    = (const float*)d_in[2];
  const float* b1    = (const float*)d_in[3];
  const float* w2    = (const float*)d_in[4];
  const float* b2    = (const float*)d_in[5];
  const float* ln_g  = (const float*)d_in[6];
  const float* ln_b  = (const float*)d_in[7];
  const float* kp_w  = (const float*)d_in[8];
  const float* rp_w  = (const float*)d_in[9];
  const float* rp_b  = (const float*)d_in[10];
  const float* out_w = (const float*)d_in[11];
  const float* out_b = (const float*)d_in[12];
  float* out = (float*)d_out;

  char* ws = (char*)d_ws;
  float* keys = (float*)ws;                               // 64*2048*128 f32 = 64 MiB
  float* Mg   = (float*)(ws + 67108864);                  // 64*128*128 f32 = 4 MiB
  float* rr   = (float*)(ws + 67108864 + 4194304);        // 64*128 f32

  hipLaunchKernelGGL(k_tokens, dim3(64*TBLK), dim3(256), 137216, stream,
                     seq, embed, w1, b1, w2, b2, ln_g, ln_b, kp_w, keys);
  hipLaunchKernelGGL(k_scan, dim3(64), dim3(512), 148608, stream, keys, Mg);
  hipLaunchKernelGGL(k_read, dim3(64), dim3(128), 0, stream, keys, Mg, rp_w, rp_b, rr);
  hipLaunchKernelGGL(k_out, dim3(250), dim3(256), 0, stream, rr, out_w, out_b, out);
}